// Round 13
// baseline (247.985 us; speedup 1.0000x reference)
//
#include <hip/hip_runtime.h>
#include <hip/hip_bf16.h>
#include <math.h>

#define S_LEN 2048
#define HID   2048
#define NH    32
#define NKV   8
#define HD    64
#define BK    64

typedef short short4x __attribute__((ext_vector_type(4)));
typedef short short8  __attribute__((ext_vector_type(8)));
typedef float floatx4 __attribute__((ext_vector_type(4)));

#define LOG2E_SC 0.180336880f   // (1/sqrt(64)) * log2(e)

static __device__ __forceinline__ ushort f2bf(float f) {
  unsigned u = __float_as_uint(f);
  u += 0x7fffu + ((u >> 16) & 1u);   // RNE; inputs finite
  return (ushort)(u >> 16);
}

// async global->LDS, 16B per lane; LDS dest = wave-uniform base + lane*16
static __device__ __forceinline__ void gl2lds16(const ushort* g, ushort* l) {
  __builtin_amdgcn_global_load_lds(
      (const __attribute__((address_space(1))) unsigned int*)g,
      (__attribute__((address_space(3))) unsigned int*)l, 16, 0, 0);
}

// ---------------- all fp32 -> bf16 conversions, one launch ----------------
#define QH  1048576
#define QW  1048576
#define QKq  262144
#define QVq  262144
#define QO  1048576
__global__ void cvt_all_kernel(const float* __restrict__ h,
                               const float* __restrict__ wq,
                               const float* __restrict__ wk,
                               const float* __restrict__ wv,
                               const float* __restrict__ wo,
                               ushort* __restrict__ hb,
                               ushort* __restrict__ wqkvb,
                               ushort* __restrict__ wob) {
  int idx = blockIdx.x * 256 + threadIdx.x;
  const float* src; ushort* dst; int so, dqo;
  if (idx < QH)                    { src = h;  dst = hb;    so = idx;                   dqo = so; }
  else if (idx < QH + QW)          { src = wq; dst = wqkvb; so = idx - QH;              dqo = so; }
  else if (idx < QH + QW + QKq)    { src = wk; dst = wqkvb; so = idx - QH - QW;         dqo = so + QW; }
  else if (idx < QH + QW + QKq + QVq) { src = wv; dst = wqkvb; so = idx - QH - QW - QKq; dqo = so + QW + QKq; }
  else                             { src = wo; dst = wob;   so = idx - QH - QW - QKq - QVq; dqo = so; }
  float4 v = ((const float4*)src)[so];
  ushort4 o;
  o.x = f2bf(v.x); o.y = f2bf(v.y); o.z = f2bf(v.z); o.w = f2bf(v.w);
  ((ushort4*)dst)[dqo] = o;
}

// ---- C[M][N] = A * B^T, 128(M)x64(N) tile, BK=64; XCD-aware 1D grid ------
__global__ __launch_bounds__(256) void gemm64_bt_kernel(
    const ushort* __restrict__ A, const ushort* __restrict__ B,
    float* __restrict__ C, int M, int N, int K, int gx) {
  __shared__ __align__(16) ushort As[128 * BK];  // 16 KB
  __shared__ __align__(16) ushort Bs[64 * BK];   //  8 KB

  const int g  = blockIdx.x & 7;
  const int s  = blockIdx.x >> 3;
  const int by = g * 2 + s / gx;
  const int bx = s % gx;

  const int tid  = threadIdx.x;
  const int wave = tid >> 6;
  const int lane = tid & 63;
  const int r16  = lane & 15;
  const int quad = lane >> 4;

  const int m_base = by * 128;
  const int n_base = bx * 64;
  const int wm = wave * 32;

  // staging: each gl2lds16 call deposits 8 rows x 64 cols (1 KB)
  const int lr8 = lane >> 3;           // row within 8-row deposit
  const int lc8 = (lane & 7) * 8;      // col
  const ushort* ag[4]; ushort* as_[4];
#pragma unroll
  for (int c = 0; c < 4; ++c) {
    ag[c]  = A + (size_t)(m_base + wave * 32 + c * 8 + lr8) * K + lc8;
    as_[c] = As + (wave * 32 + c * 8) * BK;
  }
  const ushort* bg[2]; ushort* bs_[2];
#pragma unroll
  for (int c = 0; c < 2; ++c) {
    bg[c]  = B + (size_t)(n_base + wave * 16 + c * 8 + lr8) * K + lc8;
    bs_[c] = Bs + (wave * 16 + c * 8) * BK;
  }

  floatx4 acc[2][4];
#pragma unroll
  for (int i = 0; i < 2; ++i)
#pragma unroll
    for (int j = 0; j < 4; ++j) acc[i][j] = floatx4{0.f, 0.f, 0.f, 0.f};

  for (int kk = 0; kk < K; kk += BK) {
    __syncthreads();
#pragma unroll
    for (int c = 0; c < 4; ++c) gl2lds16(ag[c] + kk, as_[c]);
#pragma unroll
    for (int c = 0; c < 2; ++c) gl2lds16(bg[c] + kk, bs_[c]);
    __syncthreads();

#pragma unroll
    for (int h2 = 0; h2 < 2; ++h2) {
      short8 af[2], bf[4];
#pragma unroll
      for (int i = 0; i < 2; ++i)
        af[i] = *(const short8*)&As[(wm + i * 16 + r16) * BK + h2 * 32 + quad * 8];
#pragma unroll
      for (int j = 0; j < 4; ++j)
        bf[j] = *(const short8*)&Bs[(j * 16 + r16) * BK + h2 * 32 + quad * 8];
#pragma unroll
      for (int i = 0; i < 2; ++i)
#pragma unroll
        for (int j = 0; j < 4; ++j)
          acc[i][j] = __builtin_amdgcn_mfma_f32_16x16x32_bf16(af[i], bf[j], acc[i][j], 0, 0, 0);
    }
  }

#pragma unroll
  for (int i = 0; i < 2; ++i)
#pragma unroll
    for (int j = 0; j < 4; ++j) {
      const int cm = m_base + wm + i * 16 + quad * 4;
      const int cn = n_base + j * 16 + r16;
#pragma unroll
      for (int r = 0; r < 4; ++r)
        C[(size_t)(cm + r) * N + cn] = acc[i][j][r];
    }
}

// ---- fused QKV GEMM (128x64, BK=64, XCD-swizzled): RoPE + layout epi -----
// Q heads are pre-scaled by LOG2E_SC (folds attn's softmax scale into RoPE).
__global__ __launch_bounds__(256) void gemm_qkv_kernel(
    const ushort* __restrict__ A, const ushort* __restrict__ B,
    const int* __restrict__ pos,
    ushort* __restrict__ qr,    // [NH][S][64]  bf16 roped, pre-scaled
    ushort* __restrict__ kr,    // [NKV][S][64] bf16 roped
    ushort* __restrict__ vtb,   // [NKV][64][S] bf16
    int gx) {
  __shared__ __align__(16) ushort As[128 * BK];
  __shared__ __align__(16) ushort Bs[64 * BK];

  const int g  = blockIdx.x & 7;
  const int s_ = blockIdx.x >> 3;
  const int by = g * 2 + s_ / gx;
  const int bx = s_ % gx;

  const int K = HID;
  const int tid  = threadIdx.x;
  const int wave = tid >> 6;
  const int lane = tid & 63;
  const int r16  = lane & 15;
  const int quad = lane >> 4;

  const int m_base = by * 128;
  const int n_base = bx * 64;
  const int wm = wave * 32;

  const int lr8 = lane >> 3;
  const int lc8 = (lane & 7) * 8;
  const ushort* ag[4]; ushort* as_[4];
#pragma unroll
  for (int c = 0; c < 4; ++c) {
    ag[c]  = A + (size_t)(m_base + wave * 32 + c * 8 + lr8) * K + lc8;
    as_[c] = As + (wave * 32 + c * 8) * BK;
  }
  const ushort* bg[2]; ushort* bs_[2];
#pragma unroll
  for (int c = 0; c < 2; ++c) {
    bg[c]  = B + (size_t)(n_base + wave * 16 + c * 8 + lr8) * K + lc8;
    bs_[c] = Bs + (wave * 16 + c * 8) * BK;
  }

  floatx4 acc[2][4];
#pragma unroll
  for (int i = 0; i < 2; ++i)
#pragma unroll
    for (int j = 0; j < 4; ++j) acc[i][j] = floatx4{0.f, 0.f, 0.f, 0.f};

  for (int kk = 0; kk < K; kk += BK) {
    __syncthreads();
#pragma unroll
    for (int c = 0; c < 4; ++c) gl2lds16(ag[c] + kk, as_[c]);
#pragma unroll
    for (int c = 0; c < 2; ++c) gl2lds16(bg[c] + kk, bs_[c]);
    __syncthreads();

#pragma unroll
    for (int h2 = 0; h2 < 2; ++h2) {
      short8 af[2], bf[4];
#pragma unroll
      for (int i = 0; i < 2; ++i)
        af[i] = *(const short8*)&As[(wm + i * 16 + r16) * BK + h2 * 32 + quad * 8];
#pragma unroll
      for (int j = 0; j < 4; ++j)
        bf[j] = *(const short8*)&Bs[(j * 16 + r16) * BK + h2 * 32 + quad * 8];
#pragma unroll
      for (int i = 0; i < 2; ++i)
#pragma unroll
        for (int j = 0; j < 4; ++j)
          acc[i][j] = __builtin_amdgcn_mfma_f32_16x16x32_bf16(af[i], bf[j], acc[i][j], 0, 0, 0);
    }
  }

  const int n0 = n_base;   // head base (block-uniform)
  if (n0 < HID + NKV * HD) {
    ushort* dst;
    if (n0 < HID) dst = qr + (size_t)(n0 >> 6) * S_LEN * 64;
    else          dst = kr + (size_t)((n0 - HID) >> 6) * S_LEN * 64;
    const float qsc = (n0 < HID) ? LOG2E_SC : 1.0f;   // pre-scale Q only
    const float invfA = powf(10000.0f, -(float)r16 * (1.0f / 32.0f));
    const float invfB = powf(10000.0f, -(float)(16 + r16) * (1.0f / 32.0f));
#pragma unroll
    for (int i = 0; i < 2; ++i) {
#pragma unroll
      for (int r = 0; r < 4; ++r) {
        const int s = m_base + wm + i * 16 + quad * 4 + r;
        const float p = (float)pos[s];
        float snA, csA, snB, csB;
        sincosf(p * invfA, &snA, &csA);
        sincosf(p * invfB, &snB, &csB);
        snA *= qsc; csA *= qsc; snB *= qsc; csB *= qsc;
        ushort* row = dst + (size_t)s * 64;
        row[r16]      = f2bf(acc[i][0][r] * csA - acc[i][2][r] * snA);
        row[16 + r16] = f2bf(acc[i][1][r] * csB - acc[i][3][r] * snB);
        row[32 + r16] = f2bf(acc[i][2][r] * csA + acc[i][0][r] * snA);
        row[48 + r16] = f2bf(acc[i][3][r] * csB + acc[i][1][r] * snB);
      }
    }
  } else {
    const int hh = (n0 - HID - NKV * HD) >> 6;
#pragma unroll
    for (int i = 0; i < 2; ++i) {
      const int s0 = m_base + wm + i * 16 + quad * 4;
#pragma unroll
      for (int j = 0; j < 4; ++j) {
        const int d = j * 16 + r16;
        ushort4 o4;
        o4.x = f2bf(acc[i][j][0]);
        o4.y = f2bf(acc[i][j][1]);
        o4.z = f2bf(acc[i][j][2]);
        o4.w = f2bf(acc[i][j][3]);
        *(ushort4*)&vtb[((size_t)hh * 64 + d) * S_LEN + s0] = o4;
      }
    }
  }
}

// ---------------- causal GQA flash attention (MFMA bf16) ------------------
// Q pre-scaled into base-2 domain -> scores go straight to exp2 (no fma,
// no static-max subtract; P<=2^9, normalized in epilogue). Packed bf16 cvt.
__global__ __launch_bounds__(256) void attn_kernel(
    const ushort* __restrict__ Q,   // [NH][S][64]  bf16 roped, pre-scaled
    const ushort* __restrict__ K,   // [NKV][S][64] bf16 roped
    const ushort* __restrict__ Vt,  // [NKV][64][S] bf16
    ushort* __restrict__ O) {       // [S][NH*64]   bf16
  __shared__ __align__(16) ushort Ks[2][64][72];   // 18 KB
  __shared__ __align__(16) ushort Vs[2][64][72];   // 18 KB
  __shared__ __align__(16) ushort Pw[4][16][72];   //  9 KB

  const int h    = blockIdx.x;
  const int kh   = h >> 2;                         // GROUPS = 4
  const int y    = blockIdx.y;
  const int qt   = (y & 1) ? (31 - (y >> 1)) : (y >> 1);  // load balance
  const int tid  = threadIdx.x;
  const int wave = tid >> 6;
  const int lane = tid & 63;
  const int r16  = lane & 15;
  const int quad = lane >> 4;

  const int q_glob = qt * 64 + wave * 16 + r16;

  const ushort* qp = Q + ((size_t)h * S_LEN + q_glob) * 64 + quad * 8;
  const short8 qf0 = *(const short8*)qp;
  const short8 qf1 = *(const short8*)(qp + 32);

  float l = 0.f;
  floatx4 oacc[4];
#pragma unroll
  for (int n = 0; n < 4; ++n) oacc[n] = floatx4{0.f, 0.f, 0.f, 0.f};

  for (int t0 = 0; t0 <= qt; t0 += 2) {
    __syncthreads();
    {  // stage 128 keys (2 tiles) of K and Vt
      const ushort* ksrc = K  + ((size_t)kh * S_LEN + t0 * 64) * 64;
      const ushort* vsrc = Vt + ((size_t)kh * 64) * S_LEN + t0 * 64;
      for (int i = tid; i < 1024; i += 256) {
        int half = i >> 9;
        int j = i & 511;
        int r = j >> 3, c = (j & 7) * 8;
        *(short8*)&Ks[half][r][c] =
            *(const short8*)(ksrc + (size_t)(half * 64 + r) * 64 + c);
        *(short8*)&Vs[half][r][c] =
            *(const short8*)(vsrc + (size_t)r * S_LEN + half * 64 + c);
      }
    }
    __syncthreads();

    const int hmax = (t0 + 1 <= qt) ? 2 : 1;
#pragma unroll 1
    for (int half = 0; half < hmax; ++half) {
      const int kt = t0 + half;

      // ---- scores transposed: S^T[key][q] (already in base-2 domain) ----
      floatx4 sacc[4];
#pragma unroll
      for (int t = 0; t < 4; ++t) {
        short8 kf0 = *(const short8*)&Ks[half][t * 16 + r16][quad * 8];
        short8 kf1 = *(const short8*)&Ks[half][t * 16 + r16][32 + quad * 8];
        floatx4 z = {0.f, 0.f, 0.f, 0.f};
        z = __builtin_amdgcn_mfma_f32_16x16x32_bf16(kf0, qf0, z, 0, 0, 0);
        sacc[t] = __builtin_amdgcn_mfma_f32_16x16x32_bf16(kf1, qf1, z, 0, 0, 0);
      }

      // ---- softmax: exp2 directly; packed bf16 cvt; P -> per-wave LDS ----
      const bool diag = (kt == qt);
      const int key0 = kt * 64 + quad * 4;
      float ps = 0.f;
#pragma unroll
      for (int t = 0; t < 4; ++t) {
        float p[4];
#pragma unroll
        for (int r = 0; r < 4; ++r) {
          float sc = sacc[t][r];
          if (diag && (key0 + t * 16 + r) > q_glob) sc = -1e30f;
          p[r] = __builtin_amdgcn_exp2f(sc);
        }
        ps += (p[0] + p[1]) + (p[2] + p[3]);
        __hip_bfloat162 plo = __float22bfloat162_rn(float2{p[0], p[1]});
        __hip_bfloat162 phi = __float22bfloat162_rn(float2{p[2], p[3]});
        uint2 u;
        u.x = *(unsigned int*)&plo;
        u.y = *(unsigned int*)&phi;
        *(uint2*)&Pw[wave][r16][t * 16 + quad * 4] = u;
      }
      l += ps;

      // ---- PV ----
      short8 pf0 = *(const short8*)&Pw[wave][r16][quad * 8];
      short8 pf1 = *(const short8*)&Pw[wave][r16][32 + quad * 8];
#pragma unroll
      for (int n = 0; n < 4; ++n) {
        short8 vf0 = *(const short8*)&Vs[half][n * 16 + r16][quad * 8];
        short8 vf1 = *(const short8*)&Vs[half][n * 16 + r16][32 + quad * 8];
        oacc[n] = __builtin_amdgcn_mfma_f32_16x16x32_bf16(vf0, pf0, oacc[n], 0, 0, 0);
        oacc[n] = __builtin_amdgcn_mfma_f32_16x16x32_bf16(vf1, pf1, oacc[n], 0, 0, 0);
      }
    }
  }

  // ---- epilogue: reduce l across quads, normalize, store ----
  l += __shfl_xor(l, 16);
  l += __shfl_xor(l, 32);
  const float inv_l = 1.f / l;
#pragma unroll
  for (int n = 0; n < 4; ++n) {
    ushort4 o4;
    o4.x = f2bf(oacc[n][0] * inv_l);
    o4.y = f2bf(oacc[n][1] * inv_l);
    o4.z = f2bf(oacc[n][2] * inv_l);
    o4.w = f2bf(oacc[n][3] * inv_l);
    *(ushort4*)&O[(size_t)q_glob * (NH * HD) + h * 64 + n * 16 + quad * 4] = o4;
  }
}

// --------------------------------------------------------------------------
extern "C" void kernel_launch(void* const* d_in, const int* in_sizes, int n_in,
                              void* d_out, int out_size, void* d_ws, size_t ws_size,
                              hipStream_t stream) {
  const float* hidden = (const float*)d_in[0];
  const int*   pos    = (const int*)d_in[2];
  const float* Wq     = (const float*)d_in[3];
  const float* Wk     = (const float*)d_in[4];
  const float* Wv     = (const float*)d_in[5];
  const float* Wo     = (const float*)d_in[6];
  float* out = (float*)d_out;

  const int NQKV = HID + 2 * NKV * HD;  // 3072

  char* w = (char*)d_ws;
  auto carve = [&](size_t bytes) { char* p = w; w += bytes; return p; };
  ushort* hb    = (ushort*)carve((size_t)S_LEN * HID * 2);
  ushort* wqkvb = (ushort*)carve((size_t)NQKV * HID * 2);
  ushort* wob   = (ushort*)carve((size_t)HID * HID * 2);
  ushort* qr    = (ushort*)carve((size_t)NH * S_LEN * HD * 2);
  ushort* kr    = (ushort*)carve((size_t)NKV * S_LEN * HD * 2);
  ushort* vtb   = (ushort*)carve((size_t)NKV * HD * S_LEN * 2);
  ushort* ob    = (ushort*)carve((size_t)S_LEN * HID * 2);

  // 1) all bf16 conversions, one launch
  cvt_all_kernel<<<(QH + QW + QKq + QVq + QO) / 256, 256, 0, stream>>>(
      hidden, Wq, Wk, Wv, Wo, hb, wqkvb, wob);

  // 2) fused QKV projection + RoPE(+Q pre-scale) + layout epilogue
  gemm_qkv_kernel<<<(NQKV / 64) * (S_LEN / 128), 256, 0, stream>>>(
      hb, wqkvb, pos, qr, kr, vtb, NQKV / 64);

  // 3) causal GQA attention (MFMA, double-k-tile) -> bf16 [S][NH*HD]
  dim3 ga(NH, S_LEN / 64);
  attn_kernel<<<ga, 256, 0, stream>>>(qr, kr, vtb, ob);

  // 4) output projection (XCD-swizzled 1D grid) -> fp32 d_out
  gemm64_bt_kernel<<<(HID / 64) * (S_LEN / 128), 256, 0, stream>>>(
      ob, wob, out, S_LEN, HID, HID, HID / 64);
}

// Round 14
// 243.367 us; speedup vs baseline: 1.0190x; 1.0190x over previous
//
#include <hip/hip_runtime.h>
#include <hip/hip_bf16.h>
#include <math.h>

#define S_LEN 2048
#define HID   2048
#define NH    32
#define NKV   8
#define HD    64
#define BK    32

typedef short short4x __attribute__((ext_vector_type(4)));
typedef short short8  __attribute__((ext_vector_type(8)));
typedef float floatx4 __attribute__((ext_vector_type(4)));

#define LOG2E_SC 0.180336880f   // (1/sqrt(64)) * log2(e)

static __device__ __forceinline__ ushort f2bf(float f) {
  unsigned u = __float_as_uint(f);
  u += 0x7fffu + ((u >> 16) & 1u);   // RNE; inputs finite
  return (ushort)(u >> 16);
}

// async global->LDS, 16B per lane; LDS dest = wave-uniform base + lane*16
static __device__ __forceinline__ void gl2lds16(const ushort* g, ushort* l) {
  __builtin_amdgcn_global_load_lds(
      (const __attribute__((address_space(1))) unsigned int*)g,
      (__attribute__((address_space(3))) unsigned int*)l, 16, 0, 0);
}

// ---------------- all fp32 -> bf16 conversions, one launch ----------------
#define QH  1048576
#define QW  1048576
#define QKq  262144
#define QVq  262144
#define QO  1048576
__global__ void cvt_all_kernel(const float* __restrict__ h,
                               const float* __restrict__ wq,
                               const float* __restrict__ wk,
                               const float* __restrict__ wv,
                               const float* __restrict__ wo,
                               ushort* __restrict__ hb,
                               ushort* __restrict__ wqkvb,
                               ushort* __restrict__ wob) {
  int idx = blockIdx.x * 256 + threadIdx.x;
  const float* src; ushort* dst; int so, dqo;
  if (idx < QH)                    { src = h;  dst = hb;    so = idx;                   dqo = so; }
  else if (idx < QH + QW)          { src = wq; dst = wqkvb; so = idx - QH;              dqo = so; }
  else if (idx < QH + QW + QKq)    { src = wk; dst = wqkvb; so = idx - QH - QW;         dqo = so + QW; }
  else if (idx < QH + QW + QKq + QVq) { src = wv; dst = wqkvb; so = idx - QH - QW - QKq; dqo = so + QW + QKq; }
  else                             { src = wo; dst = wob;   so = idx - QH - QW - QKq - QVq; dqo = so; }
  float4 v = ((const float4*)src)[so];
  ushort4 o;
  o.x = f2bf(v.x); o.y = f2bf(v.y); o.z = f2bf(v.z); o.w = f2bf(v.w);
  ((ushort4*)dst)[dqo] = o;
}

// ---- C[M][N] = A * B^T, 128(M)x64(N) tile, BK=32; XCD-aware 1D grid ------
__global__ __launch_bounds__(256) void gemm64_bt_kernel(
    const ushort* __restrict__ A, const ushort* __restrict__ B,
    float* __restrict__ C, int M, int N, int K, int gx) {
  __shared__ __align__(16) ushort As[128 * BK];  // 8 KB
  __shared__ __align__(16) ushort Bs[64 * BK];   // 4 KB

  const int g  = blockIdx.x & 7;
  const int s  = blockIdx.x >> 3;
  const int by = g * 2 + s / gx;
  const int bx = s % gx;

  const int tid  = threadIdx.x;
  const int wave = tid >> 6;
  const int lane = tid & 63;
  const int r16  = lane & 15;
  const int quad = lane >> 4;

  const int m_base = by * 128;
  const int n_base = bx * 64;
  const int wm = wave * 32;

  const int lrow = lane >> 2;          // 0..15
  const int scol = (lane & 3) * 8;
  const ushort* ag0 = A + (size_t)(m_base + wave * 32 + lrow) * K + scol;
  const ushort* ag1 = ag0 + (size_t)16 * K;
  const ushort* bg  = B + (size_t)(n_base + wave * 16 + lrow) * K + scol;
  ushort* as0 = As + (wave * 32) * BK;
  ushort* as1 = As + (wave * 32 + 16) * BK;
  ushort* bs  = Bs + (wave * 16) * BK;

  floatx4 acc[2][4];
#pragma unroll
  for (int i = 0; i < 2; ++i)
#pragma unroll
    for (int j = 0; j < 4; ++j) acc[i][j] = floatx4{0.f, 0.f, 0.f, 0.f};

  for (int kk = 0; kk < K; kk += BK) {
    __syncthreads();
    gl2lds16(ag0 + kk, as0);
    gl2lds16(ag1 + kk, as1);
    gl2lds16(bg + kk, bs);
    __syncthreads();

    short8 af[2], bf[4];
#pragma unroll
    for (int i = 0; i < 2; ++i)
      af[i] = *(const short8*)&As[(wm + i * 16 + r16) * BK + quad * 8];
#pragma unroll
    for (int j = 0; j < 4; ++j)
      bf[j] = *(const short8*)&Bs[(j * 16 + r16) * BK + quad * 8];
#pragma unroll
    for (int i = 0; i < 2; ++i)
#pragma unroll
      for (int j = 0; j < 4; ++j)
        acc[i][j] = __builtin_amdgcn_mfma_f32_16x16x32_bf16(af[i], bf[j], acc[i][j], 0, 0, 0);
  }

#pragma unroll
  for (int i = 0; i < 2; ++i)
#pragma unroll
    for (int j = 0; j < 4; ++j) {
      const int cm = m_base + wm + i * 16 + quad * 4;
      const int cn = n_base + j * 16 + r16;
#pragma unroll
      for (int r = 0; r < 4; ++r)
        C[(size_t)(cm + r) * N + cn] = acc[i][j][r];
    }
}

// ---- fused QKV GEMM (128x64, BK=32, XCD-swizzled): RoPE + layout epi -----
// Q heads pre-scaled by LOG2E_SC (folds attn's softmax scale into RoPE).
__global__ __launch_bounds__(256) void gemm_qkv_kernel(
    const ushort* __restrict__ A, const ushort* __restrict__ B,
    const int* __restrict__ pos,
    ushort* __restrict__ qr,    // [NH][S][64]  bf16 roped, pre-scaled
    ushort* __restrict__ kr,    // [NKV][S][64] bf16 roped
    ushort* __restrict__ vtb,   // [NKV][64][S] bf16
    int gx) {
  __shared__ __align__(16) ushort As[128 * BK];
  __shared__ __align__(16) ushort Bs[64 * BK];

  const int g  = blockIdx.x & 7;
  const int s_ = blockIdx.x >> 3;
  const int by = g * 2 + s_ / gx;
  const int bx = s_ % gx;

  const int K = HID;
  const int tid  = threadIdx.x;
  const int wave = tid >> 6;
  const int lane = tid & 63;
  const int r16  = lane & 15;
  const int quad = lane >> 4;

  const int m_base = by * 128;
  const int n_base = bx * 64;
  const int wm = wave * 32;

  const int lrow = lane >> 2;
  const int scol = (lane & 3) * 8;
  const ushort* ag0 = A + (size_t)(m_base + wave * 32 + lrow) * K + scol;
  const ushort* ag1 = ag0 + (size_t)16 * K;
  const ushort* bg  = B + (size_t)(n_base + wave * 16 + lrow) * K + scol;
  ushort* as0 = As + (wave * 32) * BK;
  ushort* as1 = As + (wave * 32 + 16) * BK;
  ushort* bs  = Bs + (wave * 16) * BK;

  floatx4 acc[2][4];
#pragma unroll
  for (int i = 0; i < 2; ++i)
#pragma unroll
    for (int j = 0; j < 4; ++j) acc[i][j] = floatx4{0.f, 0.f, 0.f, 0.f};

  for (int kk = 0; kk < K; kk += BK) {
    __syncthreads();
    gl2lds16(ag0 + kk, as0);
    gl2lds16(ag1 + kk, as1);
    gl2lds16(bg + kk, bs);
    __syncthreads();

    short8 af[2], bf[4];
#pragma unroll
    for (int i = 0; i < 2; ++i)
      af[i] = *(const short8*)&As[(wm + i * 16 + r16) * BK + quad * 8];
#pragma unroll
    for (int j = 0; j < 4; ++j)
      bf[j] = *(const short8*)&Bs[(j * 16 + r16) * BK + quad * 8];
#pragma unroll
    for (int i = 0; i < 2; ++i)
#pragma unroll
      for (int j = 0; j < 4; ++j)
        acc[i][j] = __builtin_amdgcn_mfma_f32_16x16x32_bf16(af[i], bf[j], acc[i][j], 0, 0, 0);
  }

  const int n0 = n_base;   // head base (block-uniform)
  if (n0 < HID + NKV * HD) {
    ushort* dst;
    if (n0 < HID) dst = qr + (size_t)(n0 >> 6) * S_LEN * 64;
    else          dst = kr + (size_t)((n0 - HID) >> 6) * S_LEN * 64;
    const float qsc = (n0 < HID) ? LOG2E_SC : 1.0f;   // pre-scale Q only
    const float invfA = powf(10000.0f, -(float)r16 * (1.0f / 32.0f));
    const float invfB = powf(10000.0f, -(float)(16 + r16) * (1.0f / 32.0f));
#pragma unroll
    for (int i = 0; i < 2; ++i) {
#pragma unroll
      for (int r = 0; r < 4; ++r) {
        const int s = m_base + wm + i * 16 + quad * 4 + r;
        const float p = (float)pos[s];
        float snA, csA, snB, csB;
        sincosf(p * invfA, &snA, &csA);
        sincosf(p * invfB, &snB, &csB);
        snA *= qsc; csA *= qsc; snB *= qsc; csB *= qsc;
        ushort* row = dst + (size_t)s * 64;
        row[r16]      = f2bf(acc[i][0][r] * csA - acc[i][2][r] * snA);
        row[16 + r16] = f2bf(acc[i][1][r] * csB - acc[i][3][r] * snB);
        row[32 + r16] = f2bf(acc[i][2][r] * csA + acc[i][0][r] * snA);
        row[48 + r16] = f2bf(acc[i][3][r] * csB + acc[i][1][r] * snB);
      }
    }
  } else {
    const int hh = (n0 - HID - NKV * HD) >> 6;
#pragma unroll
    for (int i = 0; i < 2; ++i) {
      const int s0 = m_base + wm + i * 16 + quad * 4;
#pragma unroll
      for (int j = 0; j < 4; ++j) {
        const int d = j * 16 + r16;
        ushort4 o4;
        o4.x = f2bf(acc[i][j][0]);
        o4.y = f2bf(acc[i][j][1]);
        o4.z = f2bf(acc[i][j][2]);
        o4.w = f2bf(acc[i][j][3]);
        *(ushort4*)&vtb[((size_t)hh * 64 + d) * S_LEN + s0] = o4;
      }
    }
  }
}

// ---------------- causal GQA flash attention (MFMA bf16) ------------------
// XCD-aware head decode: h = (x&7)*4 + (x>>3) puts all 128 blocks sharing a
// KV head-group on one XCD (1 MB K+V resident in its 4 MB L2).
// Q pre-scaled into base-2 domain -> scores go straight to exp2.
__global__ __launch_bounds__(256) void attn_kernel(
    const ushort* __restrict__ Q,   // [NH][S][64]  bf16 roped, pre-scaled
    const ushort* __restrict__ K,   // [NKV][S][64] bf16 roped
    const ushort* __restrict__ Vt,  // [NKV][64][S] bf16
    ushort* __restrict__ O) {       // [S][NH*64]   bf16
  __shared__ __align__(16) ushort Ks[2][64][72];   // 18 KB
  __shared__ __align__(16) ushort Vs[2][64][72];   // 18 KB
  __shared__ __align__(16) ushort Pw[4][16][72];   //  9 KB

  const int x    = blockIdx.x;
  const int h    = (x & 7) * 4 + (x >> 3);         // XCD-local KV group
  const int kh   = x & 7;                          // == h >> 2
  const int y    = blockIdx.y;
  const int qt   = (y & 1) ? (31 - (y >> 1)) : (y >> 1);  // load balance
  const int tid  = threadIdx.x;
  const int wave = tid >> 6;
  const int lane = tid & 63;
  const int r16  = lane & 15;
  const int quad = lane >> 4;

  const int q_glob = qt * 64 + wave * 16 + r16;

  const ushort* qp = Q + ((size_t)h * S_LEN + q_glob) * 64 + quad * 8;
  const short8 qf0 = *(const short8*)qp;
  const short8 qf1 = *(const short8*)(qp + 32);

  float l = 0.f;
  floatx4 oacc[4];
#pragma unroll
  for (int n = 0; n < 4; ++n) oacc[n] = floatx4{0.f, 0.f, 0.f, 0.f};

  for (int t0 = 0; t0 <= qt; t0 += 2) {
    __syncthreads();
    {  // stage 128 keys (2 tiles) of K and Vt
      const ushort* ksrc = K  + ((size_t)kh * S_LEN + t0 * 64) * 64;
      const ushort* vsrc = Vt + ((size_t)kh * 64) * S_LEN + t0 * 64;
      for (int i = tid; i < 1024; i += 256) {
        int half = i >> 9;
        int j = i & 511;
        int r = j >> 3, c = (j & 7) * 8;
        *(short8*)&Ks[half][r][c] =
            *(const short8*)(ksrc + (size_t)(half * 64 + r) * 64 + c);
        *(short8*)&Vs[half][r][c] =
            *(const short8*)(vsrc + (size_t)r * S_LEN + half * 64 + c);
      }
    }
    __syncthreads();

    const int hmax = (t0 + 1 <= qt) ? 2 : 1;
#pragma unroll 1
    for (int half = 0; half < hmax; ++half) {
      const int kt = t0 + half;

      // ---- scores transposed: S^T[key][q] (already in base-2 domain) ----
      floatx4 sacc[4];
#pragma unroll
      for (int t = 0; t < 4; ++t) {
        short8 kf0 = *(const short8*)&Ks[half][t * 16 + r16][quad * 8];
        short8 kf1 = *(const short8*)&Ks[half][t * 16 + r16][32 + quad * 8];
        floatx4 z = {0.f, 0.f, 0.f, 0.f};
        z = __builtin_amdgcn_mfma_f32_16x16x32_bf16(kf0, qf0, z, 0, 0, 0);
        sacc[t] = __builtin_amdgcn_mfma_f32_16x16x32_bf16(kf1, qf1, z, 0, 0, 0);
      }

      // ---- softmax: exp2 directly; packed bf16 cvt; P -> per-wave LDS ----
      const bool diag = (kt == qt);
      const int key0 = kt * 64 + quad * 4;
      float ps = 0.f;
#pragma unroll
      for (int t = 0; t < 4; ++t) {
        float p[4];
#pragma unroll
        for (int r = 0; r < 4; ++r) {
          float sc = sacc[t][r];
          if (diag && (key0 + t * 16 + r) > q_glob) sc = -1e30f;
          p[r] = __builtin_amdgcn_exp2f(sc);
        }
        ps += (p[0] + p[1]) + (p[2] + p[3]);
        __hip_bfloat162 plo = __float22bfloat162_rn(float2{p[0], p[1]});
        __hip_bfloat162 phi = __float22bfloat162_rn(float2{p[2], p[3]});
        uint2 u;
        u.x = *(unsigned int*)&plo;
        u.y = *(unsigned int*)&phi;
        *(uint2*)&Pw[wave][r16][t * 16 + quad * 4] = u;
      }
      l += ps;

      // ---- PV ----
      short8 pf0 = *(const short8*)&Pw[wave][r16][quad * 8];
      short8 pf1 = *(const short8*)&Pw[wave][r16][32 + quad * 8];
#pragma unroll
      for (int n = 0; n < 4; ++n) {
        short8 vf0 = *(const short8*)&Vs[half][n * 16 + r16][quad * 8];
        short8 vf1 = *(const short8*)&Vs[half][n * 16 + r16][32 + quad * 8];
        oacc[n] = __builtin_amdgcn_mfma_f32_16x16x32_bf16(vf0, pf0, oacc[n], 0, 0, 0);
        oacc[n] = __builtin_amdgcn_mfma_f32_16x16x32_bf16(vf1, pf1, oacc[n], 0, 0, 0);
      }
    }
  }

  // ---- epilogue: reduce l across quads, normalize, store ----
  l += __shfl_xor(l, 16);
  l += __shfl_xor(l, 32);
  const float inv_l = 1.f / l;
#pragma unroll
  for (int n = 0; n < 4; ++n) {
    ushort4 o4;
    o4.x = f2bf(oacc[n][0] * inv_l);
    o4.y = f2bf(oacc[n][1] * inv_l);
    o4.z = f2bf(oacc[n][2] * inv_l);
    o4.w = f2bf(oacc[n][3] * inv_l);
    *(ushort4*)&O[(size_t)q_glob * (NH * HD) + h * 64 + n * 16 + quad * 4] = o4;
  }
}

// --------------------------------------------------------------------------
extern "C" void kernel_launch(void* const* d_in, const int* in_sizes, int n_in,
                              void* d_out, int out_size, void* d_ws, size_t ws_size,
                              hipStream_t stream) {
  const float* hidden = (const float*)d_in[0];
  const int*   pos    = (const int*)d_in[2];
  const float* Wq     = (const float*)d_in[3];
  const float* Wk     = (const float*)d_in[4];
  const float* Wv     = (const float*)d_in[5];
  const float* Wo     = (const float*)d_in[6];
  float* out = (float*)d_out;

  const int NQKV = HID + 2 * NKV * HD;  // 3072

  char* w = (char*)d_ws;
  auto carve = [&](size_t bytes) { char* p = w; w += bytes; return p; };
  ushort* hb    = (ushort*)carve((size_t)S_LEN * HID * 2);
  ushort* wqkvb = (ushort*)carve((size_t)NQKV * HID * 2);
  ushort* wob   = (ushort*)carve((size_t)HID * HID * 2);
  ushort* qr    = (ushort*)carve((size_t)NH * S_LEN * HD * 2);
  ushort* kr    = (ushort*)carve((size_t)NKV * S_LEN * HD * 2);
  ushort* vtb   = (ushort*)carve((size_t)NKV * HD * S_LEN * 2);
  ushort* ob    = (ushort*)carve((size_t)S_LEN * HID * 2);

  // 1) all bf16 conversions, one launch
  cvt_all_kernel<<<(QH + QW + QKq + QVq + QO) / 256, 256, 0, stream>>>(
      hidden, Wq, Wk, Wv, Wo, hb, wqkvb, wob);

  // 2) fused QKV projection + RoPE(+Q pre-scale) + layout epilogue
  gemm_qkv_kernel<<<(NQKV / 64) * (S_LEN / 128), 256, 0, stream>>>(
      hb, wqkvb, pos, qr, kr, vtb, NQKV / 64);

  // 3) causal GQA attention (MFMA, XCD-local KV) -> bf16 [S][NH*HD]
  dim3 ga(NH, S_LEN / 64);
  attn_kernel<<<ga, 256, 0, stream>>>(qr, kr, vtb, ob);

  // 4) output projection (XCD-swizzled 1D grid) -> fp32 d_out
  gemm64_bt_kernel<<<(HID / 64) * (S_LEN / 128), 256, 0, stream>>>(
      ob, wob, out, S_LEN, HID, HID, HID / 64);
}